// Round 3
// baseline (161.101 us; speedup 1.0000x reference)
//
#include <hip/hip_runtime.h>
#include <math.h>

#define N_NODES 10000
#define N_EDGES 320000
#define F_IN 512
#define HID 256
#define PAD_DEG 80      // max in-degree ~60 (Poisson(32) over 10k nodes); 80 is +8.5 sigma
#define N_GEMM_BLKS 157 // 157 x 64 rows = 10048 >= 10000; block = 4 waves, wave = 64x64 tile
#define BUILD_BLKS ((N_EDGES + 255) / 256)   // 1250

typedef _Float16 half8 __attribute__((ext_vector_type(8)));
typedef float floatx4 __attribute__((ext_vector_type(4)));

__device__ __forceinline__ void fma4(float4& acc, float s, const float4& v) {
    acc.x += s * v.x; acc.y += s * v.y; acc.z += s * v.z; acc.w += s * v.w;
}

// ---- k_pre: zero degree counters + W1 [512][256] -> transposed fp16 hi/lo split ----

__global__ __launch_bounds__(256) void k_pre(const float* __restrict__ W1,
                                             int* __restrict__ count,
                                             _Float16* __restrict__ Bt_hi,
                                             _Float16* __restrict__ Bt_lo) {
    int i = blockIdx.x * blockDim.x + threadIdx.x;
    if (i < 10240) count[i] = 0;
    int k = i >> 8, n = i & 255;
    float v = W1[i];
    _Float16 hi = (_Float16)v;
    Bt_hi[n * F_IN + k] = hi;
    Bt_lo[n * F_IN + k] = (_Float16)(v - (float)hi);
}

// ---- k_main: zero-LDS zero-barrier GEMM (blocks 0..156) || CSR build (rest) ----
// MFMA fragments are loaded DIRECTLY from global per lane: A-frag lane l15 covers row
// mi*16+l15, k quad*8..+7 (two float4), the 4 quads jointly covering full 128B lines;
// the 4 waves of a block share the same 64 A-rows via L1/L2. B (512 KB) is L2-hot.
// No barriers -> no s_waitcnt vmcnt(0) drain -> prefetch actually stays in flight.
// CSR blocks carry no LDS now -> full occupancy, run concurrently on idle CUs.

__global__ __launch_bounds__(256) void k_main(const float* __restrict__ A,
                                              const _Float16* __restrict__ Bt_hi,
                                              const _Float16* __restrict__ Bt_lo,
                                              const float* __restrict__ b1,
                                              float* __restrict__ h0,
                                              const int* __restrict__ ei,
                                              int* __restrict__ count,
                                              int* __restrict__ csr) {
    const int tid = threadIdx.x;

    if (blockIdx.x >= N_GEMM_BLKS) {
        // ---------- CSR build half ----------
        int e = (blockIdx.x - N_GEMM_BLKS) * 256 + tid;
        if (e < N_EDGES) {
            int src = ei[e];
            int dst = ei[N_EDGES + e];
            int pos = atomicAdd(&count[dst], 1);   // final value = in-degree
            csr[dst * PAD_DEG + pos] = src;
        }
        return;
    }

    // ---------- GEMM half: h0 = feature @ W1 + b1, 3-term fp16-split MFMA ----------
    const int lane = tid & 63, w = tid >> 6;
    const int quad = lane >> 4, l15 = lane & 15;
    const int row0 = blockIdx.x * 64;
    const int colw = w * 64;                       // wave w owns cols colw..colw+63
    floatx4 acc[4][4] = {};

    const float*    aptr[4];
    const _Float16* bhptr[4];
    const _Float16* blptr[4];
    #pragma unroll
    for (int mi = 0; mi < 4; ++mi) {
        int ar = row0 + mi * 16 + l15;
        if (ar >= N_NODES) ar = N_NODES - 1;       // clamp: loads valid, store skipped
        aptr[mi] = A + (size_t)ar * F_IN + quad * 8;
    }
    #pragma unroll
    for (int ni = 0; ni < 4; ++ni) {
        int col = colw + ni * 16 + l15;
        bhptr[ni] = Bt_hi + (size_t)col * F_IN + quad * 8;
        blptr[ni] = Bt_lo + (size_t)col * F_IN + quad * 8;
    }

    // 1-deep register prefetch, no copies: cvt A -> A-prefetch -> MFMA -> B-prefetch
    float4 apf[4][2];
    half8  bhp[4], blp[4];
    #pragma unroll
    for (int mi = 0; mi < 4; ++mi) {
        apf[mi][0] = *(const float4*)(aptr[mi]);
        apf[mi][1] = *(const float4*)(aptr[mi] + 4);
    }
    #pragma unroll
    for (int ni = 0; ni < 4; ++ni) {
        bhp[ni] = *(const half8*)(bhptr[ni]);
        blp[ni] = *(const half8*)(blptr[ni]);
    }

    #pragma unroll
    for (int kk = 0; kk < 16; ++kk) {
        // convert current A slice to hi/lo fp16 (consumes apf)
        half8 ah[4], al[4];
        #pragma unroll
        for (int mi = 0; mi < 4; ++mi) {
            float av[8] = {apf[mi][0].x, apf[mi][0].y, apf[mi][0].z, apf[mi][0].w,
                           apf[mi][1].x, apf[mi][1].y, apf[mi][1].z, apf[mi][1].w};
            #pragma unroll
            for (int j = 0; j < 8; ++j) {
                _Float16 h = (_Float16)av[j];
                ah[mi][j] = h;
                al[mi][j] = (_Float16)(av[j] - (float)h);
            }
        }
        // A-prefetch for k+1 (apf free now; in flight across the MFMA cluster)
        if (kk < 15) {
            const int k1 = (kk + 1) * 32;
            #pragma unroll
            for (int mi = 0; mi < 4; ++mi) {
                apf[mi][0] = *(const float4*)(aptr[mi] + k1);
                apf[mi][1] = *(const float4*)(aptr[mi] + k1 + 4);
            }
        }
        // 48 MFMAs on current fragments
        #pragma unroll
        for (int ni = 0; ni < 4; ++ni)
            #pragma unroll
            for (int mi = 0; mi < 4; ++mi) {
                acc[mi][ni] = __builtin_amdgcn_mfma_f32_16x16x32_f16(ah[mi], bhp[ni], acc[mi][ni], 0, 0, 0);
                acc[mi][ni] = __builtin_amdgcn_mfma_f32_16x16x32_f16(ah[mi], blp[ni], acc[mi][ni], 0, 0, 0);
                acc[mi][ni] = __builtin_amdgcn_mfma_f32_16x16x32_f16(al[mi], bhp[ni], acc[mi][ni], 0, 0, 0);
            }
        // B-prefetch for k+1 (bhp/blp consumed by the MFMAs above; B is L2-resident)
        if (kk < 15) {
            const int k1 = (kk + 1) * 32;
            #pragma unroll
            for (int ni = 0; ni < 4; ++ni) {
                bhp[ni] = *(const half8*)(bhptr[ni] + k1);
                blp[ni] = *(const half8*)(blptr[ni] + k1);
            }
        }
    }

    // epilogue: C/D layout col=lane&15, row=quad*4+reg
    #pragma unroll
    for (int mi = 0; mi < 4; ++mi)
        #pragma unroll
        for (int ni = 0; ni < 4; ++ni) {
            int colb = colw + ni * 16 + l15;
            float bias = b1[colb];
            #pragma unroll
            for (int reg = 0; reg < 4; ++reg) {
                int rowb = row0 + mi * 16 + quad * 4 + reg;
                if (rowb < N_NODES) h0[(size_t)rowb * HID + colb] = acc[mi][ni][reg] + bias;
            }
        }
}

// ---- k_agg1: u0 = relu(agg(h0)) @ W2 + b2 ----
// one wave/node; neighbor list + rsqrt weights preloaded in parallel into LDS;
// inner loop now 16 independent 1KB gathers in flight (16 KB/wave) for LLC latency.

__global__ __launch_bounds__(256) void k_agg1(const float* __restrict__ h0,
                                              const int* __restrict__ csr,
                                              const int* __restrict__ count,
                                              const float* __restrict__ W2,
                                              const float* __restrict__ b2,
                                              float* __restrict__ u0) {
    __shared__ int2 nb[4][PAD_DEG];                   // {src, weight-bits} per wave
    const int wid = threadIdx.x >> 6;
    const int lane = threadIdx.x & 63;
    const int n = blockIdx.x * 4 + wid;               // grid = 2500 -> n < 10000 always
    const int deg = count[n];
    const float degd = (float)(deg > 0 ? deg : 1);
    const int* row = csr + (size_t)n * PAD_DEG;
    for (int j = lane; j < deg; j += 64) {            // parallel preload (deg <= 80)
        int s = row[j];
        int cs = count[s];
        float wq = rsqrtf((float)(cs > 0 ? cs : 1) * degd);
        nb[wid][j] = make_int2(s, __float_as_int(wq));
    }
    __syncthreads();                                  // all waves reach (no early return)

    const int off = lane << 2;
    float4 acc0 = {0,0,0,0}, acc1 = {0,0,0,0}, acc2 = {0,0,0,0}, acc3 = {0,0,0,0};
    int j = 0;
    for (; j + 16 <= deg; j += 16) {
        int2 e[16];
        #pragma unroll
        for (int q = 0; q < 16; ++q) e[q] = nb[wid][j + q];
        float4 v[16];
        #pragma unroll
        for (int q = 0; q < 16; ++q)
            v[q] = *(const float4*)(h0 + ((size_t)e[q].x << 8) + off);
        #pragma unroll
        for (int q = 0; q < 16; q += 4) {
            fma4(acc0, __int_as_float(e[q + 0].y), v[q + 0]);
            fma4(acc1, __int_as_float(e[q + 1].y), v[q + 1]);
            fma4(acc2, __int_as_float(e[q + 2].y), v[q + 2]);
            fma4(acc3, __int_as_float(e[q + 3].y), v[q + 3]);
        }
    }
    for (; j + 4 <= deg; j += 4) {
        int2 e0 = nb[wid][j+0], e1 = nb[wid][j+1], e2 = nb[wid][j+2], e3 = nb[wid][j+3];
        float4 v0 = *(const float4*)(h0 + ((size_t)e0.x << 8) + off);
        float4 v1 = *(const float4*)(h0 + ((size_t)e1.x << 8) + off);
        float4 v2 = *(const float4*)(h0 + ((size_t)e2.x << 8) + off);
        float4 v3 = *(const float4*)(h0 + ((size_t)e3.x << 8) + off);
        fma4(acc0, __int_as_float(e0.y), v0);
        fma4(acc1, __int_as_float(e1.y), v1);
        fma4(acc2, __int_as_float(e2.y), v2);
        fma4(acc3, __int_as_float(e3.y), v3);
    }
    for (; j < deg; ++j) {
        int2 e = nb[wid][j];
        float4 v = *(const float4*)(h0 + ((size_t)e.x << 8) + off);
        fma4(acc0, __int_as_float(e.y), v);
    }
    acc0.x += acc1.x + acc2.x + acc3.x;
    acc0.y += acc1.y + acc2.y + acc3.y;
    acc0.z += acc1.z + acc2.z + acc3.z;
    acc0.w += acc1.w + acc2.w + acc3.w;
    acc0.x = fmaxf(acc0.x, 0.f); acc0.y = fmaxf(acc0.y, 0.f);
    acc0.z = fmaxf(acc0.z, 0.f); acc0.w = fmaxf(acc0.w, 0.f);
    float4 wa = *(const float4*)(W2 + (lane << 3));
    float4 wb = *(const float4*)(W2 + (lane << 3) + 4);
    float p0 = acc0.x * wa.x + acc0.y * wa.z + acc0.z * wb.x + acc0.w * wb.z;
    float p1 = acc0.x * wa.y + acc0.y * wa.w + acc0.z * wb.y + acc0.w * wb.w;
    #pragma unroll
    for (int o = 32; o > 0; o >>= 1) {
        p0 += __shfl_down(p0, o);
        p1 += __shfl_down(p1, o);
    }
    if (lane == 0) {
        u0[2 * n]     = p0 + b2[0];
        u0[2 * n + 1] = p1 + b2[1];
    }
}

// ---- k_agg2: second aggregation + Lorentz->Poincare pointwise (weights inline) ----

__global__ __launch_bounds__(256) void k_agg2(const float* __restrict__ u0,
                                              const int* __restrict__ csr,
                                              const int* __restrict__ count,
                                              const float* __restrict__ scale,
                                              float* __restrict__ out) {
    int n = blockIdx.x * 4 + (threadIdx.x >> 6);
    int lane = threadIdx.x & 63;
    if (n >= N_NODES) return;
    int deg = count[n];
    float degd = (float)(deg > 0 ? deg : 1);
    const int* row = csr + (size_t)n * PAD_DEG;
    float a0 = 0.f, a1 = 0.f;
    for (int j = lane; j < deg; j += 64) {
        int s = row[j];
        int cs = count[s];
        float wq = rsqrtf((float)(cs > 0 ? cs : 1) * degd);
        float2 uv = *(const float2*)(u0 + 2 * (size_t)s);
        a0 += wq * uv.x;
        a1 += wq * uv.y;
    }
    #pragma unroll
    for (int o = 32; o > 0; o >>= 1) {
        a0 += __shfl_down(a0, o);
        a1 += __shfl_down(a1, o);
    }
    if (lane == 0) {
        float un = fmaxf(sqrtf(a0 * a0 + a1 * a1), 1e-15f);
        float t = tanhf(0.5f * un) / un;   // sinh/(1+cosh)==tanh(x/2), overflow-proof
        float p0 = a0 * t, p1 = a1 * t;
        float pn = fmaxf(sqrtf(p0 * p0 + p1 * p1), 1e-12f);
        float s = fminf(fmaxf(scale[0], 0.666f), 0.999f);
        p0 = p0 / pn * s; p1 = p1 / pn * s;
        float nn = fmaxf(sqrtf(p0 * p0 + p1 * p1), 1e-15f);
        if (nn > 1.0f) { p0 = p0 / nn; p1 = p1 / nn; }   // (1-1e-15)==1.0f in fp32
        out[2 * n]     = p0;
        out[2 * n + 1] = p1;
    }
}

// ---------------- launch ----------------

extern "C" void kernel_launch(void* const* d_in, const int* in_sizes, int n_in,
                              void* d_out, int out_size, void* d_ws, size_t ws_size,
                              hipStream_t stream) {
    const float* feature = (const float*)d_in[0];
    const int*   ei      = (const int*)d_in[1];
    const float* W1      = (const float*)d_in[2];
    const float* b1      = (const float*)d_in[3];
    const float* W2      = (const float*)d_in[4];
    const float* b2      = (const float*)d_in[5];
    const float* scale   = (const float*)d_in[6];
    float* out = (float*)d_out;

    // workspace layout (byte offsets, all 16B-aligned)
    char* W = (char*)d_ws;
    int*      count = (int*)W;                    // 10240 ints
    int*      csr   = (int*)(W + 40960);          // 800000 ints
    float*    h0    = (float*)(W + 3240960);      // 10000*256 fp32
    float*    u0    = (float*)(W + 13480960);     // 20000 floats
    _Float16* Bt_hi = (_Float16*)(W + 13560960);  // 256*512 halves
    _Float16* Bt_lo = (_Float16*)(W + 13823104);  // 256*512 halves  (~14.1 MB total)

    k_pre<<<dim3(512), dim3(256), 0, stream>>>(W1, count, Bt_hi, Bt_lo);
    k_main<<<dim3(N_GEMM_BLKS + BUILD_BLKS), dim3(256), 0, stream>>>(
        feature, Bt_hi, Bt_lo, b1, h0, ei, count, csr);
    k_agg1<<<dim3((N_NODES + 3) / 4), dim3(256), 0, stream>>>(h0, csr, count, W2, b2, u0);
    k_agg2<<<dim3((N_NODES + 3) / 4), dim3(256), 0, stream>>>(u0, csr, count, scale, out);
}

// Round 4
// 150.814 us; speedup vs baseline: 1.0682x; 1.0682x over previous
//
#include <hip/hip_runtime.h>
#include <math.h>

#define N_NODES 10000
#define N_EDGES 320000
#define F_IN 512
#define HID 256
#define PAD_DEG 80      // max in-degree ~60 (Poisson(32) over 10k nodes); 80 is +8.5 sigma
#define N_GEMM_BLKS 632 // 158 row-panels' worth: 79 panels x 4 col-tiles, padded to 632 = 8*79
#define BUILD_BLKS ((N_EDGES + 255) / 256)   // 1250

typedef _Float16 half8 __attribute__((ext_vector_type(8)));
typedef float floatx4 __attribute__((ext_vector_type(4)));

typedef const __attribute__((address_space(1))) void* gas_ptr;
typedef __attribute__((address_space(3))) void* las_ptr;

// async global->LDS DMA, 16B per lane; LDS dst = wave-uniform base + lane*16
__device__ __forceinline__ void dma16(const void* g, void* l) {
    __builtin_amdgcn_global_load_lds((gas_ptr)g, (las_ptr)l, 16, 0, 0);
}

__device__ __forceinline__ void fma4(float4& acc, float s, const float4& v) {
    acc.x += s * v.x; acc.y += s * v.y; acc.z += s * v.z; acc.w += s * v.w;
}

// ---- k_pre: zero degree counters + W1 [512][256] -> transposed fp16 hi/lo split ----

__global__ __launch_bounds__(256) void k_pre(const float* __restrict__ W1,
                                             int* __restrict__ count,
                                             _Float16* __restrict__ Bt_hi,
                                             _Float16* __restrict__ Bt_lo) {
    int i = blockIdx.x * blockDim.x + threadIdx.x;
    if (i < 10240) count[i] = 0;
    int k = i >> 8, n = i & 255;
    float v = W1[i];
    _Float16 hi = (_Float16)v;
    Bt_hi[n * F_IN + k] = hi;
    Bt_lo[n * F_IN + k] = (_Float16)(v - (float)hi);
}

// ---- k_main: DMA-fed GEMM (blocks 0..631) || CSR build (blocks 632..1881) ----
// 64x64 tiles, 628 real blocks (~2.5/CU): cross-block overlap hides barrier drains.
// A (fp32) + B hi/lo (fp16) staged via global_load_lds width-16, double-buffered,
// one barrier/iter. Source-side XOR chunk swizzle makes all ds_read_b128 fragment
// reads bank-conflict-free. XCD swizzle keeps a row-panel's 4 col-tiles on one L2.

__global__ __launch_bounds__(256) void k_main(const float* __restrict__ A,
                                              const _Float16* __restrict__ Bt_hi,
                                              const _Float16* __restrict__ Bt_lo,
                                              const float* __restrict__ b1,
                                              float* __restrict__ h0,
                                              const int* __restrict__ ei,
                                              int* __restrict__ count,
                                              int* __restrict__ csr) {
    __shared__ float    As[2][2048];     // [buf][64 rows x 32 k] fp32, chunk-swizzled
    __shared__ _Float16 Bhs[2][2048];    // [buf][64 cols x 32 k] fp16 hi, chunk-swizzled
    __shared__ _Float16 Bls[2][2048];    // [buf][64 cols x 32 k] fp16 lo
    const int tid = threadIdx.x;

    if (blockIdx.x >= N_GEMM_BLKS) {
        // ---------- CSR build half ----------
        int e = (blockIdx.x - N_GEMM_BLKS) * 256 + tid;
        if (e < N_EDGES) {
            int src = ei[e];
            int dst = ei[N_EDGES + e];
            int pos = atomicAdd(&count[dst], 1);   // final value = in-degree
            csr[dst * PAD_DEG + pos] = src;
        }
        return;
    }

    // ---------- GEMM half: h0 = feature @ W1 + b1, 3-term fp16-split MFMA ----------
    // XCD swizzle: blocks with same (blockIdx&7) cover a contiguous tile range so the
    // 4 col-tiles of each 64-row A panel share one XCD's L2.
    const int b = blockIdx.x;
    const int t = (b & 7) * 79 + (b >> 3);          // bijective over 0..631
    const int row0 = (t >> 2) * 64, col0 = (t & 3) * 64;   // t>=628 -> row0>=10048: pad blk

    // --- DMA source addresses (constant per thread; k0 added per iter) ---
    // A: 512 slots of 16B; slot s holds chunk (row=s>>3, h=(s&7)^(row&7)) of [64][32]f32
    const int sA0 = tid, sA1 = tid + 256;
    const int rA0 = sA0 >> 3, hA0 = (sA0 & 7) ^ (rA0 & 7);
    const int rA1 = sA1 >> 3, hA1 = (sA1 & 7) ^ (rA1 & 7);
    int gr0 = row0 + rA0; if (gr0 > N_NODES - 1) gr0 = N_NODES - 1;   // clamp pad rows
    int gr1 = row0 + rA1; if (gr1 > N_NODES - 1) gr1 = N_NODES - 1;
    const float* gA0 = A + (size_t)gr0 * F_IN + hA0 * 4;
    const float* gA1 = A + (size_t)gr1 * F_IN + hA1 * 4;
    // B: 256 slots of 16B; slot s holds chunk (col=s>>2, h=(s&3)^(col&3)) of [64][32]f16
    const int cB = tid >> 2, hB = (tid & 3) ^ (cB & 3);
    const _Float16* gBh = Bt_hi + (size_t)(col0 + cB) * F_IN + hB * 8;
    const _Float16* gBl = Bt_lo + (size_t)(col0 + cB) * F_IN + hB * 8;

    char* lA  = (char*)&As[0][0];    // buffer stride 8192 B
    char* lBh = (char*)&Bhs[0][0];   // buffer stride 4096 B
    char* lBl = (char*)&Bls[0][0];
    const int dA0 = sA0 * 16, dA1 = sA1 * 16, dB = tid * 16;

    // prologue: tile 0 -> buf 0
    dma16(gA0, lA + dA0);
    dma16(gA1, lA + dA1);
    dma16(gBh, lBh + dB);
    dma16(gBl, lBl + dB);

    const int lane = tid & 63, w = tid >> 6;
    const int quad = lane >> 4, l15 = lane & 15;
    const int wm = (w >> 1) * 32, wn = (w & 1) * 32;   // wave = 32x32 sub-tile
    floatx4 acc[2][2] = {};

    // fragment LDS byte offsets (swizzled; constant per lane)
    int aoff[2][2], boff[2];
    #pragma unroll
    for (int mi = 0; mi < 2; ++mi) {
        int r = wm + mi * 16 + l15;
        aoff[mi][0] = r * 128 + ((2 * quad)     ^ (r & 7)) * 16;
        aoff[mi][1] = r * 128 + ((2 * quad + 1) ^ (r & 7)) * 16;
    }
    #pragma unroll
    for (int ni = 0; ni < 2; ++ni) {
        int n = wn + ni * 16 + l15;
        boff[ni] = n * 64 + (quad ^ (n & 3)) * 16;
    }

    __syncthreads();                                   // tile 0 resident

    int buf = 0;
    for (int it = 0; it < 16; ++it) {
        // issue next tile's DMA into buf^1 (stays in flight under compute)
        if (it < 15) {
            const int k1 = (it + 1) * 32;
            const int nb = buf ^ 1;
            dma16(gA0 + k1, lA  + nb * 8192 + dA0);
            dma16(gA1 + k1, lA  + nb * 8192 + dA1);
            dma16(gBh + k1, lBh + nb * 4096 + dB);
            dma16(gBl + k1, lBl + nb * 4096 + dB);
        }
        // compute from buf
        const char* bA = lA  + buf * 8192;
        const char* bH = lBh + buf * 4096;
        const char* bL = lBl + buf * 4096;
        half8 ah[2], al[2], bhf[2], blf[2];
        #pragma unroll
        for (int mi = 0; mi < 2; ++mi) {
            float4 f0 = *(const float4*)(bA + aoff[mi][0]);
            float4 f1 = *(const float4*)(bA + aoff[mi][1]);
            float av[8] = {f0.x, f0.y, f0.z, f0.w, f1.x, f1.y, f1.z, f1.w};
            #pragma unroll
            for (int j = 0; j < 8; ++j) {
                _Float16 h = (_Float16)av[j];
                ah[mi][j] = h;
                al[mi][j] = (_Float16)(av[j] - (float)h);
            }
        }
        #pragma unroll
        for (int ni = 0; ni < 2; ++ni) {
            bhf[ni] = *(const half8*)(bH + boff[ni]);
            blf[ni] = *(const half8*)(bL + boff[ni]);
        }
        #pragma unroll
        for (int ni = 0; ni < 2; ++ni)
            #pragma unroll
            for (int mi = 0; mi < 2; ++mi) {
                acc[mi][ni] = __builtin_amdgcn_mfma_f32_16x16x32_f16(ah[mi], bhf[ni], acc[mi][ni], 0, 0, 0);
                acc[mi][ni] = __builtin_amdgcn_mfma_f32_16x16x32_f16(ah[mi], blf[ni], acc[mi][ni], 0, 0, 0);
                acc[mi][ni] = __builtin_amdgcn_mfma_f32_16x16x32_f16(al[mi], bhf[ni], acc[mi][ni], 0, 0, 0);
            }
        __syncthreads();   // drains DMA (next tile ready) + all reads of buf done
        buf ^= 1;
    }

    // epilogue: C/D layout col=lane&15, row=quad*4+reg
    #pragma unroll
    for (int mi = 0; mi < 2; ++mi)
        #pragma unroll
        for (int ni = 0; ni < 2; ++ni) {
            int colb = col0 + wn + ni * 16 + l15;
            float bias = b1[colb];
            #pragma unroll
            for (int reg = 0; reg < 4; ++reg) {
                int rowb = row0 + wm + mi * 16 + quad * 4 + reg;
                if (rowb < N_NODES) h0[(size_t)rowb * HID + colb] = acc[mi][ni][reg] + bias;
            }
        }
}

// ---- k_agg1: u0 = relu(agg(h0)) @ W2 + b2 ----
// one wave/node; neighbor list + rsqrt weights preloaded in parallel into LDS;
// inner loop 16 independent 1KB gathers in flight (16 KB/wave) for LLC latency.

__global__ __launch_bounds__(256) void k_agg1(const float* __restrict__ h0,
                                              const int* __restrict__ csr,
                                              const int* __restrict__ count,
                                              const float* __restrict__ W2,
                                              const float* __restrict__ b2,
                                              float* __restrict__ u0) {
    __shared__ int2 nb[4][PAD_DEG];                   // {src, weight-bits} per wave
    const int wid = threadIdx.x >> 6;
    const int lane = threadIdx.x & 63;
    const int n = blockIdx.x * 4 + wid;               // grid = 2500 -> n < 10000 always
    const int deg = count[n];
    const float degd = (float)(deg > 0 ? deg : 1);
    const int* row = csr + (size_t)n * PAD_DEG;
    for (int j = lane; j < deg; j += 64) {            // parallel preload (deg <= 80)
        int s = row[j];
        int cs = count[s];
        float wq = rsqrtf((float)(cs > 0 ? cs : 1) * degd);
        nb[wid][j] = make_int2(s, __float_as_int(wq));
    }
    __syncthreads();                                  // all waves reach (no early return)

    const int off = lane << 2;
    float4 acc0 = {0,0,0,0}, acc1 = {0,0,0,0}, acc2 = {0,0,0,0}, acc3 = {0,0,0,0};
    int j = 0;
    for (; j + 16 <= deg; j += 16) {
        int2 e[16];
        #pragma unroll
        for (int q = 0; q < 16; ++q) e[q] = nb[wid][j + q];
        float4 v[16];
        #pragma unroll
        for (int q = 0; q < 16; ++q)
            v[q] = *(const float4*)(h0 + ((size_t)e[q].x << 8) + off);
        #pragma unroll
        for (int q = 0; q < 16; q += 4) {
            fma4(acc0, __int_as_float(e[q + 0].y), v[q + 0]);
            fma4(acc1, __int_as_float(e[q + 1].y), v[q + 1]);
            fma4(acc2, __int_as_float(e[q + 2].y), v[q + 2]);
            fma4(acc3, __int_as_float(e[q + 3].y), v[q + 3]);
        }
    }
    for (; j + 4 <= deg; j += 4) {
        int2 e0 = nb[wid][j+0], e1 = nb[wid][j+1], e2 = nb[wid][j+2], e3 = nb[wid][j+3];
        float4 v0 = *(const float4*)(h0 + ((size_t)e0.x << 8) + off);
        float4 v1 = *(const float4*)(h0 + ((size_t)e1.x << 8) + off);
        float4 v2 = *(const float4*)(h0 + ((size_t)e2.x << 8) + off);
        float4 v3 = *(const float4*)(h0 + ((size_t)e3.x << 8) + off);
        fma4(acc0, __int_as_float(e0.y), v0);
        fma4(acc1, __int_as_float(e1.y), v1);
        fma4(acc2, __int_as_float(e2.y), v2);
        fma4(acc3, __int_as_float(e3.y), v3);
    }
    for (; j < deg; ++j) {
        int2 e = nb[wid][j];
        float4 v = *(const float4*)(h0 + ((size_t)e.x << 8) + off);
        fma4(acc0, __int_as_float(e.y), v);
    }
    acc0.x += acc1.x + acc2.x + acc3.x;
    acc0.y += acc1.y + acc2.y + acc3.y;
    acc0.z += acc1.z + acc2.z + acc3.z;
    acc0.w += acc1.w + acc2.w + acc3.w;
    acc0.x = fmaxf(acc0.x, 0.f); acc0.y = fmaxf(acc0.y, 0.f);
    acc0.z = fmaxf(acc0.z, 0.f); acc0.w = fmaxf(acc0.w, 0.f);
    float4 wa = *(const float4*)(W2 + (lane << 3));
    float4 wb = *(const float4*)(W2 + (lane << 3) + 4);
    float p0 = acc0.x * wa.x + acc0.y * wa.z + acc0.z * wb.x + acc0.w * wb.z;
    float p1 = acc0.x * wa.y + acc0.y * wa.w + acc0.z * wb.y + acc0.w * wb.w;
    #pragma unroll
    for (int o = 32; o > 0; o >>= 1) {
        p0 += __shfl_down(p0, o);
        p1 += __shfl_down(p1, o);
    }
    if (lane == 0) {
        u0[2 * n]     = p0 + b2[0];
        u0[2 * n + 1] = p1 + b2[1];
    }
}

// ---- k_agg2: second aggregation + Lorentz->Poincare pointwise (weights inline) ----

__global__ __launch_bounds__(256) void k_agg2(const float* __restrict__ u0,
                                              const int* __restrict__ csr,
                                              const int* __restrict__ count,
                                              const float* __restrict__ scale,
                                              float* __restrict__ out) {
    int n = blockIdx.x * 4 + (threadIdx.x >> 6);
    int lane = threadIdx.x & 63;
    if (n >= N_NODES) return;
    int deg = count[n];
    float degd = (float)(deg > 0 ? deg : 1);
    const int* row = csr + (size_t)n * PAD_DEG;
    float a0 = 0.f, a1 = 0.f;
    for (int j = lane; j < deg; j += 64) {
        int s = row[j];
        int cs = count[s];
        float wq = rsqrtf((float)(cs > 0 ? cs : 1) * degd);
        float2 uv = *(const float2*)(u0 + 2 * (size_t)s);
        a0 += wq * uv.x;
        a1 += wq * uv.y;
    }
    #pragma unroll
    for (int o = 32; o > 0; o >>= 1) {
        a0 += __shfl_down(a0, o);
        a1 += __shfl_down(a1, o);
    }
    if (lane == 0) {
        float un = fmaxf(sqrtf(a0 * a0 + a1 * a1), 1e-15f);
        float t = tanhf(0.5f * un) / un;   // sinh/(1+cosh)==tanh(x/2), overflow-proof
        float p0 = a0 * t, p1 = a1 * t;
        float pn = fmaxf(sqrtf(p0 * p0 + p1 * p1), 1e-12f);
        float s = fminf(fmaxf(scale[0], 0.666f), 0.999f);
        p0 = p0 / pn * s; p1 = p1 / pn * s;
        float nn = fmaxf(sqrtf(p0 * p0 + p1 * p1), 1e-15f);
        if (nn > 1.0f) { p0 = p0 / nn; p1 = p1 / nn; }   // (1-1e-15)==1.0f in fp32
        out[2 * n]     = p0;
        out[2 * n + 1] = p1;
    }
}

// ---------------- launch ----------------

extern "C" void kernel_launch(void* const* d_in, const int* in_sizes, int n_in,
                              void* d_out, int out_size, void* d_ws, size_t ws_size,
                              hipStream_t stream) {
    const float* feature = (const float*)d_in[0];
    const int*   ei      = (const int*)d_in[1];
    const float* W1      = (const float*)d_in[2];
    const float* b1      = (const float*)d_in[3];
    const float* W2      = (const float*)d_in[4];
    const float* b2      = (const float*)d_in[5];
    const float* scale   = (const float*)d_in[6];
    float* out = (float*)d_out;

    // workspace layout (byte offsets, all 16B-aligned)
    char* W = (char*)d_ws;
    int*      count = (int*)W;                    // 10240 ints
    int*      csr   = (int*)(W + 40960);          // 800000 ints
    float*    h0    = (float*)(W + 3240960);      // 10000*256 fp32
    float*    u0    = (float*)(W + 13480960);     // 20000 floats
    _Float16* Bt_hi = (_Float16*)(W + 13560960);  // 256*512 halves
    _Float16* Bt_lo = (_Float16*)(W + 13823104);  // 256*512 halves  (~14.1 MB total)

    k_pre<<<dim3(512), dim3(256), 0, stream>>>(W1, count, Bt_hi, Bt_lo);
    k_main<<<dim3(N_GEMM_BLKS + BUILD_BLKS), dim3(256), 0, stream>>>(
        feature, Bt_hi, Bt_lo, b1, h0, ei, count, csr);
    k_agg1<<<dim3((N_NODES + 3) / 4), dim3(256), 0, stream>>>(h0, csr, count, W2, b2, u0);
    k_agg2<<<dim3((N_NODES + 3) / 4), dim3(256), 0, stream>>>(u0, csr, count, scale, out);
}

// Round 5
// 148.410 us; speedup vs baseline: 1.0855x; 1.0162x over previous
//
#include <hip/hip_runtime.h>
#include <math.h>

#define N_NODES 10000
#define N_EDGES 320000
#define F_IN 512
#define HID 256
#define PAD_DEG 80      // max in-degree ~60 (Poisson(32) over 10k nodes); 80 is +8.5 sigma
#define N_GEMM_BLKS 632 // 79 row-panels x 4 col-tiles = 628, padded to 632 = 8*79
#define BUILD_BLKS ((N_EDGES + 255) / 256)   // 1250

typedef _Float16 half8 __attribute__((ext_vector_type(8)));
typedef float floatx4 __attribute__((ext_vector_type(4)));

typedef const __attribute__((address_space(1))) void* gas_ptr;
typedef __attribute__((address_space(3))) void* las_ptr;

// async global->LDS DMA, 16B per lane; LDS dst MUST be wave-uniform (HW adds lane*16)
__device__ __forceinline__ void dma16(const void* g, void* l) {
    __builtin_amdgcn_global_load_lds((gas_ptr)g, (las_ptr)l, 16, 0, 0);
}

__device__ __forceinline__ void fma4(float4& acc, float s, const float4& v) {
    acc.x += s * v.x; acc.y += s * v.y; acc.z += s * v.z; acc.w += s * v.w;
}

// ---- k_pre: zero degree counters + W1 [512][256] -> transposed fp16 hi/lo split ----

__global__ __launch_bounds__(256) void k_pre(const float* __restrict__ W1,
                                             int* __restrict__ count,
                                             _Float16* __restrict__ Bt_hi,
                                             _Float16* __restrict__ Bt_lo) {
    int i = blockIdx.x * blockDim.x + threadIdx.x;
    if (i < 10240) count[i] = 0;
    int k = i >> 8, n = i & 255;
    float v = W1[i];
    _Float16 hi = (_Float16)v;
    Bt_hi[n * F_IN + k] = hi;
    Bt_lo[n * F_IN + k] = (_Float16)(v - (float)hi);
}

// ---- k_main: DMA-fed GEMM (blocks 0..631) || CSR build (blocks 632..1881) ----
// 64x64 tiles, double-buffered LDS, one barrier/iter. THIS ROUND: the LDS dst of
// every global_load_lds is a readfirstlane-forced WAVE-UNIFORM base (wave w owns
// slots w*64..w*64+63, base = w*1024 B); HW appends lane*16. The per-lane (and
// XOR-swizzled) addressing lives entirely on the GLOBAL source side, per m173.
// Effective addresses identical to round 4 -- only the uniformity proof changed.

__global__ __launch_bounds__(256) void k_main(const float* __restrict__ A,
                                              const _Float16* __restrict__ Bt_hi,
                                              const _Float16* __restrict__ Bt_lo,
                                              const float* __restrict__ b1,
                                              float* __restrict__ h0,
                                              const int* __restrict__ ei,
                                              int* __restrict__ count,
                                              int* __restrict__ csr) {
    __shared__ float    As[2][2048];     // [buf][64 rows x 32 k] fp32, chunk-swizzled
    __shared__ _Float16 Bhs[2][2048];    // [buf][64 cols x 32 k] fp16 hi, chunk-swizzled
    __shared__ _Float16 Bls[2][2048];    // [buf][64 cols x 32 k] fp16 lo
    const int tid = threadIdx.x;

    if (blockIdx.x >= N_GEMM_BLKS) {
        // ---------- CSR build half ----------
        int e = (blockIdx.x - N_GEMM_BLKS) * 256 + tid;
        if (e < N_EDGES) {
            int src = ei[e];
            int dst = ei[N_EDGES + e];
            int pos = atomicAdd(&count[dst], 1);   // final value = in-degree
            csr[dst * PAD_DEG + pos] = src;
        }
        return;
    }

    // ---------- GEMM half: h0 = feature @ W1 + b1, 3-term fp16-split MFMA ----------
    const int b = blockIdx.x;
    const int t = (b & 7) * 79 + (b >> 3);          // XCD swizzle, bijective over 0..631
    const int row0 = (t >> 2) * 64, col0 = (t & 3) * 64;   // t>=628 -> pad block

    // --- per-lane GLOBAL source addresses (carry the XOR chunk swizzle) ---
    // A: 512 slots of 16B; slot s holds chunk (row=s>>3, h=(s&7)^(row&7)) of [64][32]f32
    const int sA0 = tid, sA1 = tid + 256;
    const int rA0 = sA0 >> 3, hA0 = (sA0 & 7) ^ (rA0 & 7);
    const int rA1 = sA1 >> 3, hA1 = (sA1 & 7) ^ (rA1 & 7);
    int gr0 = row0 + rA0; if (gr0 > N_NODES - 1) gr0 = N_NODES - 1;   // clamp pad rows
    int gr1 = row0 + rA1; if (gr1 > N_NODES - 1) gr1 = N_NODES - 1;
    const float* gA0 = A + (size_t)gr0 * F_IN + hA0 * 4;
    const float* gA1 = A + (size_t)gr1 * F_IN + hA1 * 4;
    // B: 256 slots of 16B; slot s holds chunk (col=s>>2, h=(s&3)^(col&3)) of [64][32]f16
    const int cB = tid >> 2, hB = (tid & 3) ^ (cB & 3);
    const _Float16* gBh = Bt_hi + (size_t)(col0 + cB) * F_IN + hB * 8;
    const _Float16* gBl = Bt_lo + (size_t)(col0 + cB) * F_IN + hB * 8;

    // --- WAVE-UNIFORM LDS destinations (SGPR via readfirstlane) ---
    const int wdma = __builtin_amdgcn_readfirstlane(tid >> 6);  // wave id 0..3
    char* lA  = (char*)&As[0][0];    // buffer stride 8192 B
    char* lBh = (char*)&Bhs[0][0];   // buffer stride 4096 B
    char* lBl = (char*)&Bls[0][0];
    const int dA0u = wdma * 1024;            // A slots  w*64 .. w*64+63
    const int dA1u = 4096 + wdma * 1024;     // A slots  256+w*64 ..
    const int dBu  = wdma * 1024;            // B slots  w*64 .. w*64+63

    // prologue: tile 0 -> buf 0
    dma16(gA0, lA + dA0u);
    dma16(gA1, lA + dA1u);
    dma16(gBh, lBh + dBu);
    dma16(gBl, lBl + dBu);

    const int lane = tid & 63, w = tid >> 6;
    const int quad = lane >> 4, l15 = lane & 15;
    const int wm = (w >> 1) * 32, wn = (w & 1) * 32;   // wave = 32x32 sub-tile
    floatx4 acc[2][2] = {};

    // fragment LDS byte offsets (swizzled; constant per lane)
    int aoff[2][2], boff[2];
    #pragma unroll
    for (int mi = 0; mi < 2; ++mi) {
        int r = wm + mi * 16 + l15;
        aoff[mi][0] = r * 128 + ((2 * quad)     ^ (r & 7)) * 16;
        aoff[mi][1] = r * 128 + ((2 * quad + 1) ^ (r & 7)) * 16;
    }
    #pragma unroll
    for (int ni = 0; ni < 2; ++ni) {
        int n = wn + ni * 16 + l15;
        boff[ni] = n * 64 + (quad ^ (n & 3)) * 16;
    }

    __syncthreads();                                   // tile 0 resident

    int buf = 0;
    for (int it = 0; it < 16; ++it) {
        // issue next tile's DMA into buf^1 (stays in flight under compute)
        if (it < 15) {
            const int k1 = (it + 1) * 32;
            const int nb = buf ^ 1;
            dma16(gA0 + k1, lA  + nb * 8192 + dA0u);
            dma16(gA1 + k1, lA  + nb * 8192 + dA1u);
            dma16(gBh + k1, lBh + nb * 4096 + dBu);
            dma16(gBl + k1, lBl + nb * 4096 + dBu);
        }
        // compute from buf
        const char* bA = lA  + buf * 8192;
        const char* bH = lBh + buf * 4096;
        const char* bL = lBl + buf * 4096;
        half8 ah[2], al[2], bhf[2], blf[2];
        #pragma unroll
        for (int mi = 0; mi < 2; ++mi) {
            float4 f0 = *(const float4*)(bA + aoff[mi][0]);
            float4 f1 = *(const float4*)(bA + aoff[mi][1]);
            float av[8] = {f0.x, f0.y, f0.z, f0.w, f1.x, f1.y, f1.z, f1.w};
            #pragma unroll
            for (int j = 0; j < 8; ++j) {
                _Float16 h = (_Float16)av[j];
                ah[mi][j] = h;
                al[mi][j] = (_Float16)(av[j] - (float)h);
            }
        }
        #pragma unroll
        for (int ni = 0; ni < 2; ++ni) {
            bhf[ni] = *(const half8*)(bH + boff[ni]);
            blf[ni] = *(const half8*)(bL + boff[ni]);
        }
        #pragma unroll
        for (int ni = 0; ni < 2; ++ni)
            #pragma unroll
            for (int mi = 0; mi < 2; ++mi) {
                acc[mi][ni] = __builtin_amdgcn_mfma_f32_16x16x32_f16(ah[mi], bhf[ni], acc[mi][ni], 0, 0, 0);
                acc[mi][ni] = __builtin_amdgcn_mfma_f32_16x16x32_f16(ah[mi], blf[ni], acc[mi][ni], 0, 0, 0);
                acc[mi][ni] = __builtin_amdgcn_mfma_f32_16x16x32_f16(al[mi], bhf[ni], acc[mi][ni], 0, 0, 0);
            }
        __syncthreads();   // drains DMA (next tile ready) + all reads of buf done
        buf ^= 1;
    }

    // epilogue: C/D layout col=lane&15, row=quad*4+reg
    #pragma unroll
    for (int mi = 0; mi < 2; ++mi)
        #pragma unroll
        for (int ni = 0; ni < 2; ++ni) {
            int colb = col0 + wn + ni * 16 + l15;
            float bias = b1[colb];
            #pragma unroll
            for (int reg = 0; reg < 4; ++reg) {
                int rowb = row0 + wm + mi * 16 + quad * 4 + reg;
                if (rowb < N_NODES) h0[(size_t)rowb * HID + colb] = acc[mi][ni][reg] + bias;
            }
        }
}

// ---- k_agg1: u0 = relu(agg(h0)) @ W2 + b2 ----
// one wave/node; neighbor list + rsqrt weights preloaded in parallel into LDS;
// inner loop 16 independent 1KB gathers in flight (16 KB/wave) for LLC latency.

__global__ __launch_bounds__(256) void k_agg1(const float* __restrict__ h0,
                                              const int* __restrict__ csr,
                                              const int* __restrict__ count,
                                              const float* __restrict__ W2,
                                              const float* __restrict__ b2,
                                              float* __restrict__ u0) {
    __shared__ int2 nb[4][PAD_DEG];                   // {src, weight-bits} per wave
    const int wid = threadIdx.x >> 6;
    const int lane = threadIdx.x & 63;
    const int n = blockIdx.x * 4 + wid;               // grid = 2500 -> n < 10000 always
    const int deg = count[n];
    const float degd = (float)(deg > 0 ? deg : 1);
    const int* row = csr + (size_t)n * PAD_DEG;
    for (int j = lane; j < deg; j += 64) {            // parallel preload (deg <= 80)
        int s = row[j];
        int cs = count[s];
        float wq = rsqrtf((float)(cs > 0 ? cs : 1) * degd);
        nb[wid][j] = make_int2(s, __float_as_int(wq));
    }
    __syncthreads();                                  // all waves reach (no early return)

    const int off = lane << 2;
    float4 acc0 = {0,0,0,0}, acc1 = {0,0,0,0}, acc2 = {0,0,0,0}, acc3 = {0,0,0,0};
    int j = 0;
    for (; j + 16 <= deg; j += 16) {
        int2 e[16];
        #pragma unroll
        for (int q = 0; q < 16; ++q) e[q] = nb[wid][j + q];
        float4 v[16];
        #pragma unroll
        for (int q = 0; q < 16; ++q)
            v[q] = *(const float4*)(h0 + ((size_t)e[q].x << 8) + off);
        #pragma unroll
        for (int q = 0; q < 16; q += 4) {
            fma4(acc0, __int_as_float(e[q + 0].y), v[q + 0]);
            fma4(acc1, __int_as_float(e[q + 1].y), v[q + 1]);
            fma4(acc2, __int_as_float(e[q + 2].y), v[q + 2]);
            fma4(acc3, __int_as_float(e[q + 3].y), v[q + 3]);
        }
    }
    for (; j + 4 <= deg; j += 4) {
        int2 e0 = nb[wid][j+0], e1 = nb[wid][j+1], e2 = nb[wid][j+2], e3 = nb[wid][j+3];
        float4 v0 = *(const float4*)(h0 + ((size_t)e0.x << 8) + off);
        float4 v1 = *(const float4*)(h0 + ((size_t)e1.x << 8) + off);
        float4 v2 = *(const float4*)(h0 + ((size_t)e2.x << 8) + off);
        float4 v3 = *(const float4*)(h0 + ((size_t)e3.x << 8) + off);
        fma4(acc0, __int_as_float(e0.y), v0);
        fma4(acc1, __int_as_float(e1.y), v1);
        fma4(acc2, __int_as_float(e2.y), v2);
        fma4(acc3, __int_as_float(e3.y), v3);
    }
    for (; j < deg; ++j) {
        int2 e = nb[wid][j];
        float4 v = *(const float4*)(h0 + ((size_t)e.x << 8) + off);
        fma4(acc0, __int_as_float(e.y), v);
    }
    acc0.x += acc1.x + acc2.x + acc3.x;
    acc0.y += acc1.y + acc2.y + acc3.y;
    acc0.z += acc1.z + acc2.z + acc3.z;
    acc0.w += acc1.w + acc2.w + acc3.w;
    acc0.x = fmaxf(acc0.x, 0.f); acc0.y = fmaxf(acc0.y, 0.f);
    acc0.z = fmaxf(acc0.z, 0.f); acc0.w = fmaxf(acc0.w, 0.f);
    float4 wa = *(const float4*)(W2 + (lane << 3));
    float4 wb = *(const float4*)(W2 + (lane << 3) + 4);
    float p0 = acc0.x * wa.x + acc0.y * wa.z + acc0.z * wb.x + acc0.w * wb.z;
    float p1 = acc0.x * wa.y + acc0.y * wa.w + acc0.z * wb.y + acc0.w * wb.w;
    #pragma unroll
    for (int o = 32; o > 0; o >>= 1) {
        p0 += __shfl_down(p0, o);
        p1 += __shfl_down(p1, o);
    }
    if (lane == 0) {
        u0[2 * n]     = p0 + b2[0];
        u0[2 * n + 1] = p1 + b2[1];
    }
}

// ---- k_agg2: second aggregation + Lorentz->Poincare pointwise (weights inline) ----

__global__ __launch_bounds__(256) void k_agg2(const float* __restrict__ u0,
                                              const int* __restrict__ csr,
                                              const int* __restrict__ count,
                                              const float* __restrict__ scale,
                                              float* __restrict__ out) {
    int n = blockIdx.x * 4 + (threadIdx.x >> 6);
    int lane = threadIdx.x & 63;
    if (n >= N_NODES) return;
    int deg = count[n];
    float degd = (float)(deg > 0 ? deg : 1);
    const int* row = csr + (size_t)n * PAD_DEG;
    float a0 = 0.f, a1 = 0.f;
    for (int j = lane; j < deg; j += 64) {
        int s = row[j];
        int cs = count[s];
        float wq = rsqrtf((float)(cs > 0 ? cs : 1) * degd);
        float2 uv = *(const float2*)(u0 + 2 * (size_t)s);
        a0 += wq * uv.x;
        a1 += wq * uv.y;
    }
    #pragma unroll
    for (int o = 32; o > 0; o >>= 1) {
        a0 += __shfl_down(a0, o);
        a1 += __shfl_down(a1, o);
    }
    if (lane == 0) {
        float un = fmaxf(sqrtf(a0 * a0 + a1 * a1), 1e-15f);
        float t = tanhf(0.5f * un) / un;   // sinh/(1+cosh)==tanh(x/2), overflow-proof
        float p0 = a0 * t, p1 = a1 * t;
        float pn = fmaxf(sqrtf(p0 * p0 + p1 * p1), 1e-12f);
        float s = fminf(fmaxf(scale[0], 0.666f), 0.999f);
        p0 = p0 / pn * s; p1 = p1 / pn * s;
        float nn = fmaxf(sqrtf(p0 * p0 + p1 * p1), 1e-15f);
        if (nn > 1.0f) { p0 = p0 / nn; p1 = p1 / nn; }   // (1-1e-15)==1.0f in fp32
        out[2 * n]     = p0;
        out[2 * n + 1] = p1;
    }
}

// ---------------- launch ----------------

extern "C" void kernel_launch(void* const* d_in, const int* in_sizes, int n_in,
                              void* d_out, int out_size, void* d_ws, size_t ws_size,
                              hipStream_t stream) {
    const float* feature = (const float*)d_in[0];
    const int*   ei      = (const int*)d_in[1];
    const float* W1      = (const float*)d_in[2];
    const float* b1      = (const float*)d_in[3];
    const float* W2      = (const float*)d_in[4];
    const float* b2      = (const float*)d_in[5];
    const float* scale   = (const float*)d_in[6];
    float* out = (float*)d_out;

    // workspace layout (byte offsets, all 16B-aligned)
    char* W = (char*)d_ws;
    int*      count = (int*)W;                    // 10240 ints
    int*      csr   = (int*)(W + 40960);          // 800000 ints
    float*    h0    = (float*)(W + 3240960);      // 10000*256 fp32
    float*    u0    = (float*)(W + 13480960);     // 20000 floats
    _Float16* Bt_hi = (_Float16*)(W + 13560960);  // 256*512 halves
    _Float16* Bt_lo = (_Float16*)(W + 13823104);  // 256*512 halves  (~14.1 MB total)

    k_pre<<<dim3(512), dim3(256), 0, stream>>>(W1, count, Bt_hi, Bt_lo);
    k_main<<<dim3(N_GEMM_BLKS + BUILD_BLKS), dim3(256), 0, stream>>>(
        feature, Bt_hi, Bt_lo, b1, h0, ei, count, csr);
    k_agg1<<<dim3((N_NODES + 3) / 4), dim3(256), 0, stream>>>(h0, csr, count, W2, b2, u0);
    k_agg2<<<dim3((N_NODES + 3) / 4), dim3(256), 0, stream>>>(u0, csr, count, scale, out);
}